// Round 9
// baseline (63.489 us; speedup 1.0000x reference)
//
#include <hip/hip_runtime.h>

#define NB 16
#define NA 76725
#define NC 8
#define NM 32
#define FEPS 1e-4f
#define TPB 256
#define NBLK_X ((NA + TPB - 1) / TPB)   // 300

// ws layout (floats):
//  [WS_ACC .. +NB*16)   per-image acc: {cls_sum, reg_sum, npos(uint), pad..} 64B stride
//  [WS_NVP .. +16)      padded valid count per image
//  [WS_CNT .. +16)      num_valid per image
//  [WS_REC .. +NB*NM*8) per (b,m) record {x1,y1,x2+1,y2+1,area2,lab,pad,pad} (32B)
//  [WS_EPI .. +NB*NM*4) per (b,m) float4 {gcx,gcy,log(gw),log(gh)}
#define WS_ACC 0
#define WS_NVP (NB * 16)            // 256
#define WS_CNT (WS_NVP + 16)        // 272
#define WS_REC (WS_CNT + 16)        // 288 (16B aligned)
#define WS_EPI (WS_REC + NB * NM * 8)

__global__ __launch_bounds__(64) void focal_prep(
    const float* __restrict__ ann_, float* __restrict__ ws)
{
    const int b = blockIdx.x;
    const int m = threadIdx.x;
    if (m < 16) ws[WS_ACC + b * 16 + m] = 0.f;   // zero this image's acc line
    bool valid = false;
    float x1 = 0.f, y1 = 0.f, x2 = 0.f, y2 = 0.f, lab = -1.f;
    if (m < NM) {
        const float* r = ann_ + ((size_t)b * NM + m) * 5;
        x1 = r[0]; y1 = r[1]; x2 = r[2]; y2 = r[3]; lab = r[4];
        valid = lab > -0.5f;
        // sentinel record: inter==0 -> never beats init (ib=0, ub=1)
        float* rec = ws + WS_REC + ((size_t)b * NM + m) * 8;
        rec[0] = 3e18f; rec[1] = 3e18f; rec[2] = -3e18f; rec[3] = -3e18f;
        rec[4] = 1.0f;  rec[5] = -1.f;  rec[6] = 0.f;    rec[7] = 0.f;
        reinterpret_cast<float4*>(ws + WS_EPI)[b * NM + m] = make_float4(0.f, 0.f, 0.f, 0.f);
    }
    const unsigned long long mask = __ballot(valid);
    const int cnt = __popcll(mask);
    __syncthreads();
    if (valid) {
        const int idx = __popcll(mask & ((1ull << m) - 1ull));  // stable compaction
        float* rec = ws + WS_REC + ((size_t)b * NM + idx) * 8;
        rec[0] = x1; rec[1] = y1; rec[2] = x2 + 1.f; rec[3] = y2 + 1.f;
        rec[4] = (x2 - x1 + 1.f) * (y2 - y1 + 1.f);
        rec[5] = lab;
        const float w0 = x2 - x1, h0 = y2 - y1;
        reinterpret_cast<float4*>(ws + WS_EPI)[b * NM + idx] =
            make_float4(x1 + 0.5f * w0, y1 + 0.5f * h0,
                        __logf(fmaxf(w0, 1.f)), __logf(fmaxf(h0, 1.f)));
    }
    if (m == 0) {
        ws[WS_CNT + b] = (float)cnt;
        ws[WS_NVP + b] = (float)((cnt + 7) & ~7);
    }
}

// APT=1: max TLP (19,200 waves). Dual even/odd argmax chains give intra-thread
// ILP. Schedule: {anchor load + table load} -> barrier (drains both) ->
// {rg/cls loads pinned} -> m-loop (hides their latency) -> epilogue.
__global__ __launch_bounds__(TPB, 4) void focal_main(
    const float* __restrict__ cls_,
    const float* __restrict__ reg_,
    const float* __restrict__ anch_,
    const float* __restrict__ tab,
    float* __restrict__ acc)
{
    const int b   = blockIdx.y;
    const int tid = threadIdx.x;

    const int a = blockIdx.x * TPB + tid;
    const bool amask = (a < NA);
    const size_t base = (size_t)b * NA + (amask ? a : (NA - 1));

    // anchor load first: needed by the m-loop right after the barrier
    const float4 an = reinterpret_cast<const float4*>(anch_)[base];

    __shared__ float4 s_box[NM];          // {x1,y1,x2+1,y2+1}: ds_read_b128/m
    __shared__ float  s_a2[NM], s_lab[NM];
    __shared__ float4 s_epi[NM];
    if (tid < NM) {
        const float4 r0 = reinterpret_cast<const float4*>(tab + WS_REC)[(b * NM + tid) * 2];
        const float4 r1 = reinterpret_cast<const float4*>(tab + WS_REC)[(b * NM + tid) * 2 + 1];
        s_box[tid] = r0;
        s_a2[tid] = r1.x; s_lab[tid] = r1.y;
        s_epi[tid] = reinterpret_cast<const float4*>(tab + WS_EPI)[b * NM + tid];
    }
    int nvp = (int)tab[WS_NVP + b];
    nvp = __builtin_amdgcn_readfirstlane(nvp);   // wave-uniform scalar loop bound
    __syncthreads();   // drains anchor+table loads together

    // issue the epilogue loads now; latency hides under the m-loop
    const float4 rg  = reinterpret_cast<const float4*>(reg_)[base];
    const float4 cv0 = reinterpret_cast<const float4*>(cls_)[base * 2];
    const float4 cv1 = reinterpret_cast<const float4*>(cls_)[base * 2 + 1];
    __builtin_amdgcn_sched_barrier(0);   // pin: loads stay above the m-loop

    const float ax = an.x, ay = an.y;
    const float az1 = an.z + 1.f, aw1 = an.w + 1.f;
    const float area1 = (an.z - ax + 1.f) * (an.w - ay + 1.f);

    float ib0 = 0.f, ub0 = 1.f, ib1 = 0.f, ub1 = 1.f;
    int   arg0 = 0, arg1 = 0;

    // nvp multiple of 8 -> m+=2 safe; even/odd independent chains
    #pragma unroll 4
    for (int m = 0; m < nvp; m += 2) {
        const float4 q0 = s_box[m];        // broadcast ds_read_b128
        const float  a20 = s_a2[m];
        const float4 q1 = s_box[m + 1];
        const float  a21 = s_a2[m + 1];
        {
            const float w = fminf(az1, q0.z) - fmaxf(ax, q0.x);
            const float h = fminf(aw1, q0.w) - fmaxf(ay, q0.y);
            const float inter = fmaxf(w, 0.f) * fmaxf(h, 0.f);
            const float u = area1 + a20 - inter;
            const bool better = inter * ub0 > ib0 * u;   // strict >: first-occurrence
            ib0  = better ? inter : ib0;
            ub0  = better ? u : ub0;
            arg0 = better ? m : arg0;
        }
        {
            const float w = fminf(az1, q1.z) - fmaxf(ax, q1.x);
            const float h = fminf(aw1, q1.w) - fmaxf(ay, q1.y);
            const float inter = fmaxf(w, 0.f) * fmaxf(h, 0.f);
            const float u = area1 + a21 - inter;
            const bool better = inter * ub1 > ib1 * u;
            ib1  = better ? inter : ib1;
            ub1  = better ? u : ub1;
            arg1 = better ? m + 1 : arg1;
        }
    }

    // merge chains; exact first-occurrence tie-break (equal ratio -> lower m)
    const float c0 = ib0 * ub1;
    const float c1 = ib1 * ub0;
    const bool take1 = (c1 > c0) || (c1 == c0 && arg1 < arg0);
    const float ib = take1 ? ib1 : ib0;
    const float ub = take1 ? ub1 : ub0;
    const int   arg = take1 ? arg1 : arg0;

    const bool pos = ib >= 0.4f * ub;
    const bool neg = ib <  0.3f * ub;
    const bool act = (pos || neg) && amask;

    float cls_c = 0.f, reg_c = 0.f;
    unsigned pos_c = 0;

    {
        const float pv[8] = {cv0.x, cv0.y, cv0.z, cv0.w, cv1.x, cv1.y, cv1.z, cv1.w};
        float pcl[8];
        float bsum = 0.f;
        #pragma unroll
        for (int c = 0; c < NC; ++c) {
            const float p = fminf(fmaxf(pv[c], FEPS), 1.f - FEPS);
            pcl[c] = p;
            bsum += 0.75f * p * p * (-__logf(1.f - p));   // 8 independent chains
        }
        float contrib = bsum;
        if (pos) {
            const int labi = (int)s_lab[arg];
            const float t0 = (labi & 1) ? pcl[1] : pcl[0];
            const float t1 = (labi & 1) ? pcl[3] : pcl[2];
            const float t2 = (labi & 1) ? pcl[5] : pcl[4];
            const float t3 = (labi & 1) ? pcl[7] : pcl[6];
            const float u0 = (labi & 2) ? t1 : t0;
            const float u1 = (labi & 2) ? t3 : t2;
            const float pt = (labi & 4) ? u1 : u0;
            const float om = 1.f - pt;
            contrib += 0.25f * om * om * (-__logf(pt))
                     - 0.75f * pt * pt * (-__logf(om));
        }
        cls_c = act ? contrib : 0.f;
    }

    if (pos && amask) {
        pos_c = 1;
        const float4 ep = s_epi[arg];
        const float awd = az1 - 1.f - ax;    // no +1 for regression geometry
        const float ahd = aw1 - 1.f - ay;
        const float acx = ax + 0.5f * awd;
        const float acy = ay + 0.5f * ahd;
        const float t0 = __fdividef(ep.x - acx, awd) * 10.f;
        const float t1 = __fdividef(ep.y - acy, ahd) * 10.f;
        const float t2 = (ep.z - __logf(awd)) * 5.f;
        const float t3 = (ep.w - __logf(ahd)) * 5.f;
        const float d0 = fabsf(t0 - rg.x);
        const float d1 = fabsf(t1 - rg.y);
        const float d2 = fabsf(t2 - rg.z);
        const float d3 = fabsf(t3 - rg.w);
        auto sl1 = [](float d) {
            return d <= (1.f / 9.f) ? 4.5f * d * d : d - (0.5f / 9.f);
        };
        reg_c = sl1(d0) + sl1(d1) + sl1(d2) + sl1(d3);
    }

    // wave-64 shuffle reduction, cross-wave via LDS, 3 atomics per block
    #pragma unroll
    for (int off = 32; off > 0; off >>= 1) {
        cls_c += __shfl_down(cls_c, off);
        reg_c += __shfl_down(reg_c, off);
        pos_c += __shfl_down(pos_c, off);
    }
    __shared__ float    sc[4], sr[4];
    __shared__ unsigned sp[4];
    const int wave = tid >> 6, lane = tid & 63;
    if (lane == 0) { sc[wave] = cls_c; sr[wave] = reg_c; sp[wave] = pos_c; }
    __syncthreads();
    if (tid == 0) {
        const float    c = sc[0] + sc[1] + sc[2] + sc[3];
        const float    r = sr[0] + sr[1] + sr[2] + sr[3];
        const unsigned p = sp[0] + sp[1] + sp[2] + sp[3];
        atomicAdd(&acc[WS_ACC + b * 16 + 0], c);
        atomicAdd(&acc[WS_ACC + b * 16 + 1], r);
        atomicAdd(reinterpret_cast<unsigned*>(acc) + WS_ACC + b * 16 + 2, p);
    }
}

__global__ __launch_bounds__(64) void focal_finalize(
    const float* __restrict__ ws, float* __restrict__ out)
{
    __shared__ float s_cls[NB], s_reg[NB];
    const int b = threadIdx.x;
    if (b < NB) {
        const float    nv      = ws[WS_CNT + b];
        const float    cls_sum = ws[WS_ACC + b * 16 + 0];
        const float    reg_sum = ws[WS_ACC + b * 16 + 1];
        const unsigned npos    = reinterpret_cast<const unsigned*>(ws)[WS_ACC + b * 16 + 2];
        float cl = cls_sum / fmaxf((float)npos, 1.f);
        float rl = (npos > 0u) ? reg_sum / (float)(npos * 4u) : 0.f;
        if (nv < 0.5f) { cl = 0.f; rl = 0.f; }
        s_cls[b] = cl;
        s_reg[b] = rl;
    }
    __syncthreads();
    if (threadIdx.x == 0) {
        float c = 0.f, r = 0.f;
        for (int i = 0; i < NB; ++i) { c += s_cls[i]; r += s_reg[i]; }
        out[0] = c * (1.f / NB);
        out[1] = r * (1.f / NB);
    }
}

extern "C" void kernel_launch(void* const* d_in, const int* in_sizes, int n_in,
                              void* d_out, int out_size, void* d_ws, size_t ws_size,
                              hipStream_t stream)
{
    const float* cls_  = (const float*)d_in[0];
    const float* reg_  = (const float*)d_in[1];
    const float* anch_ = (const float*)d_in[2];
    const float* ann_  = (const float*)d_in[3];
    float* ws  = (float*)d_ws;
    float* out = (float*)d_out;

    focal_prep<<<NB, 64, 0, stream>>>(ann_, ws);
    dim3 grid(NBLK_X, NB);
    focal_main<<<grid, dim3(TPB), 0, stream>>>(cls_, reg_, anch_, ws, ws);
    focal_finalize<<<1, 64, 0, stream>>>(ws, out);
}

// Round 10
// 47.504 us; speedup vs baseline: 1.3365x; 1.3365x over previous
//
#include <hip/hip_runtime.h>

#define NB 16
#define NA 76725
#define NC 8
#define NM 32
#define FEPS 1e-4f
#define APT 2                     // anchors per thread
#define TPB 256
#define ANCH_PER_BLK (APT * TPB)  // 512
#define NBLK_X ((NA + ANCH_PER_BLK - 1) / ANCH_PER_BLK)   // 150

// ws layout (floats):
//  [WS_ACC .. +NB*16)   per-image acc: {cls_sum, reg_sum, npos(uint), pad..} 64B stride
//  [WS_NVP .. +16)      padded valid count per image
//  [WS_CNT .. +16)      num_valid per image
//  [WS_REC .. +NB*NM*8) per (b,m) record {x1,y1,x2+1,y2+1,area2,lab,pad,pad} (32B)
//  [WS_EPI .. +NB*NM*4) per (b,m) float4 {gcx,gcy,log(gw),log(gh)}
#define WS_ACC 0
#define WS_NVP (NB * 16)            // 256
#define WS_CNT (WS_NVP + 16)        // 272
#define WS_REC (WS_CNT + 16)        // 288 (16B aligned)
#define WS_EPI (WS_REC + NB * NM * 8)

__global__ __launch_bounds__(64) void focal_prep(
    const float* __restrict__ ann_, float* __restrict__ ws)
{
    const int b = blockIdx.x;
    const int m = threadIdx.x;
    if (m < 16) ws[WS_ACC + b * 16 + m] = 0.f;   // zero this image's acc line
    bool valid = false;
    float x1 = 0.f, y1 = 0.f, x2 = 0.f, y2 = 0.f, lab = -1.f;
    if (m < NM) {
        const float* r = ann_ + ((size_t)b * NM + m) * 5;
        x1 = r[0]; y1 = r[1]; x2 = r[2]; y2 = r[3]; lab = r[4];
        valid = lab > -0.5f;
        // sentinel record: inter==0 -> never beats init (ib=0, ub=1)
        float* rec = ws + WS_REC + ((size_t)b * NM + m) * 8;
        rec[0] = 3e18f; rec[1] = 3e18f; rec[2] = -3e18f; rec[3] = -3e18f;
        rec[4] = 1.0f;  rec[5] = -1.f;  rec[6] = 0.f;    rec[7] = 0.f;
        reinterpret_cast<float4*>(ws + WS_EPI)[b * NM + m] = make_float4(0.f, 0.f, 0.f, 0.f);
    }
    const unsigned long long mask = __ballot(valid);
    const int cnt = __popcll(mask);
    __syncthreads();
    if (valid) {
        const int idx = __popcll(mask & ((1ull << m) - 1ull));  // stable compaction
        float* rec = ws + WS_REC + ((size_t)b * NM + idx) * 8;
        rec[0] = x1; rec[1] = y1; rec[2] = x2 + 1.f; rec[3] = y2 + 1.f;
        rec[4] = (x2 - x1 + 1.f) * (y2 - y1 + 1.f);
        rec[5] = lab;
        const float w0 = x2 - x1, h0 = y2 - y1;
        reinterpret_cast<float4*>(ws + WS_EPI)[b * NM + idx] =
            make_float4(x1 + 0.5f * w0, y1 + 0.5f * h0,
                        __logf(fmaxf(w0, 1.f)), __logf(fmaxf(h0, 1.f)));
    }
    if (m == 0) {
        ws[WS_CNT + b] = (float)cnt;
        ws[WS_NVP + b] = (float)((cnt + 7) & ~7);
    }
}

// Exact R7 structure (proven best: 45.4 us total) with ONE change: the m-loop
// is specialized for nvp==24 (the actual workload) as a FULL unroll, so the
// compiler can pipeline all 120 LDS broadcast reads with compile-time
// addresses instead of 4-iteration windows. Generic path kept for any nvp.
__global__ __launch_bounds__(TPB, 4) void focal_main(
    const float* __restrict__ cls_,
    const float* __restrict__ reg_,
    const float* __restrict__ anch_,
    const float* __restrict__ tab,
    float* __restrict__ acc)
{
    const int b   = blockIdx.y;
    const int tid = threadIdx.x;

    __shared__ float  s_x1[NM], s_y1[NM], s_x21[NM], s_y21[NM], s_a2[NM], s_lab[NM];
    __shared__ float4 s_epi[NM];
    if (tid < NM) {
        const float4 r0 = reinterpret_cast<const float4*>(tab + WS_REC)[(b * NM + tid) * 2];
        const float4 r1 = reinterpret_cast<const float4*>(tab + WS_REC)[(b * NM + tid) * 2 + 1];
        s_x1[tid] = r0.x; s_y1[tid] = r0.y; s_x21[tid] = r0.z; s_y21[tid] = r0.w;
        s_a2[tid] = r1.x; s_lab[tid] = r1.y;
        s_epi[tid] = reinterpret_cast<const float4*>(tab + WS_EPI)[b * NM + tid];
    }
    int nvp = (int)tab[WS_NVP + b];
    nvp = __builtin_amdgcn_readfirstlane(nvp);   // wave-uniform scalar loop bound
    __syncthreads();

    const int a0 = blockIdx.x * ANCH_PER_BLK + tid;

    // ---- issue ALL global loads up front (8x dwordx4 in flight per thread)
    bool   amask[APT];
    float4 an[APT], rg[APT], cv0[APT], cv1[APT];
    #pragma unroll
    for (int k = 0; k < APT; ++k) {
        const int a = a0 + k * TPB;
        amask[k] = (a < NA);
        const int ac = amask[k] ? a : (NA - 1);        // clamp, mask later
        const size_t base = (size_t)b * NA + ac;
        an[k]  = reinterpret_cast<const float4*>(anch_)[base];
        rg[k]  = reinterpret_cast<const float4*>(reg_)[base];
        cv0[k] = reinterpret_cast<const float4*>(cls_)[base * 2];
        cv1[k] = reinterpret_cast<const float4*>(cls_)[base * 2 + 1];
    }
    // Pin the cluster: scheduler can't serialize the 8 loads (R4/R6 fix).
    __builtin_amdgcn_sched_barrier(0);

    float ax[APT], ay[APT], az1[APT], aw1[APT], area1[APT];
    float ib[APT], ub[APT];
    int   arg[APT];
    #pragma unroll
    for (int k = 0; k < APT; ++k) {
        ax[k]  = an[k].x; ay[k] = an[k].y;
        az1[k] = an[k].z + 1.f; aw1[k] = an[k].w + 1.f;
        area1[k] = (an[k].z - ax[k] + 1.f) * (an[k].w - ay[k] + 1.f);
        ib[k] = 0.f; ub[k] = 1.f; arg[k] = 0;
    }

    auto body = [&](int m) {
        const float x1 = s_x1[m], y1 = s_y1[m];        // LDS broadcast reads
        const float x21 = s_x21[m], y21 = s_y21[m];
        const float a2 = s_a2[m];
        #pragma unroll
        for (int k = 0; k < APT; ++k) {
            const float w = fminf(az1[k], x21) - fmaxf(ax[k], x1);
            const float h = fminf(aw1[k], y21) - fmaxf(ay[k], y1);
            const float inter = fmaxf(w, 0.f) * fmaxf(h, 0.f);
            const float u = area1[k] + a2 - inter;
            const bool better = inter * ub[k] > ib[k] * u;  // strict >: first-occurrence
            ib[k]  = better ? inter : ib[k];
            ub[k]  = better ? u : ub[k];
            arg[k] = better ? m : arg[k];
        }
    };

    if (nvp == 24) {
        // compile-time trip count: all 120 LDS reads get static addresses,
        // compiler pipelines them freely (ds_read2 pairing, deep lgkmcnt)
        #pragma unroll
        for (int m = 0; m < 24; ++m) body(m);
    } else {
        #pragma unroll 8
        for (int m = 0; m < nvp; ++m) body(m);
    }

    float cls_c = 0.f, reg_c = 0.f;
    unsigned pos_c = 0;

    #pragma unroll
    for (int k = 0; k < APT; ++k) {
        const bool pos = ib[k] >= 0.4f * ub[k];
        const bool neg = ib[k] <  0.3f * ub[k];
        const bool act = (pos || neg) && amask[k];

        float pcl[8];
        {
            const float pv[8] = {cv0[k].x, cv0[k].y, cv0[k].z, cv0[k].w,
                                 cv1[k].x, cv1[k].y, cv1[k].z, cv1[k].w};
            float bsum = 0.f;
            #pragma unroll
            for (int c = 0; c < NC; ++c) {
                const float p = fminf(fmaxf(pv[c], FEPS), 1.f - FEPS);
                pcl[c] = p;
                bsum += 0.75f * p * p * (-__logf(1.f - p));   // 8 independent chains
            }
            float contrib = bsum;
            if (pos) {
                const int labi = (int)s_lab[arg[k]];
                const float t0 = (labi & 1) ? pcl[1] : pcl[0];
                const float t1 = (labi & 1) ? pcl[3] : pcl[2];
                const float t2 = (labi & 1) ? pcl[5] : pcl[4];
                const float t3 = (labi & 1) ? pcl[7] : pcl[6];
                const float u0 = (labi & 2) ? t1 : t0;
                const float u1 = (labi & 2) ? t3 : t2;
                const float pt = (labi & 4) ? u1 : u0;
                const float om = 1.f - pt;
                contrib += 0.25f * om * om * (-__logf(pt))
                         - 0.75f * pt * pt * (-__logf(om));
            }
            cls_c += act ? contrib : 0.f;
        }

        if (pos && amask[k]) {
            pos_c += 1;
            const float4 ep = s_epi[arg[k]];
            const float awd = az1[k] - 1.f - ax[k];    // no +1 for regression geometry
            const float ahd = aw1[k] - 1.f - ay[k];
            const float acx = ax[k] + 0.5f * awd;
            const float acy = ay[k] + 0.5f * ahd;
            const float t0 = __fdividef(ep.x - acx, awd) * 10.f;
            const float t1 = __fdividef(ep.y - acy, ahd) * 10.f;
            const float t2 = (ep.z - __logf(awd)) * 5.f;
            const float t3 = (ep.w - __logf(ahd)) * 5.f;
            const float d0 = fabsf(t0 - rg[k].x);
            const float d1 = fabsf(t1 - rg[k].y);
            const float d2 = fabsf(t2 - rg[k].z);
            const float d3 = fabsf(t3 - rg[k].w);
            auto sl1 = [](float d) {
                return d <= (1.f / 9.f) ? 4.5f * d * d : d - (0.5f / 9.f);
            };
            reg_c += sl1(d0) + sl1(d1) + sl1(d2) + sl1(d3);
        }
    }

    // wave-64 shuffle reduction, cross-wave via LDS, 3 atomics per block
    #pragma unroll
    for (int off = 32; off > 0; off >>= 1) {
        cls_c += __shfl_down(cls_c, off);
        reg_c += __shfl_down(reg_c, off);
        pos_c += __shfl_down(pos_c, off);
    }
    __shared__ float    sc[4], sr[4];
    __shared__ unsigned sp[4];
    const int wave = tid >> 6, lane = tid & 63;
    if (lane == 0) { sc[wave] = cls_c; sr[wave] = reg_c; sp[wave] = pos_c; }
    __syncthreads();
    if (tid == 0) {
        const float    c = sc[0] + sc[1] + sc[2] + sc[3];
        const float    r = sr[0] + sr[1] + sr[2] + sr[3];
        const unsigned p = sp[0] + sp[1] + sp[2] + sp[3];
        atomicAdd(&acc[WS_ACC + b * 16 + 0], c);
        atomicAdd(&acc[WS_ACC + b * 16 + 1], r);
        atomicAdd(reinterpret_cast<unsigned*>(acc) + WS_ACC + b * 16 + 2, p);
    }
}

__global__ __launch_bounds__(64) void focal_finalize(
    const float* __restrict__ ws, float* __restrict__ out)
{
    __shared__ float s_cls[NB], s_reg[NB];
    const int b = threadIdx.x;
    if (b < NB) {
        const float    nv      = ws[WS_CNT + b];
        const float    cls_sum = ws[WS_ACC + b * 16 + 0];
        const float    reg_sum = ws[WS_ACC + b * 16 + 1];
        const unsigned npos    = reinterpret_cast<const unsigned*>(ws)[WS_ACC + b * 16 + 2];
        float cl = cls_sum / fmaxf((float)npos, 1.f);
        float rl = (npos > 0u) ? reg_sum / (float)(npos * 4u) : 0.f;
        if (nv < 0.5f) { cl = 0.f; rl = 0.f; }
        s_cls[b] = cl;
        s_reg[b] = rl;
    }
    __syncthreads();
    if (threadIdx.x == 0) {
        float c = 0.f, r = 0.f;
        for (int i = 0; i < NB; ++i) { c += s_cls[i]; r += s_reg[i]; }
        out[0] = c * (1.f / NB);
        out[1] = r * (1.f / NB);
    }
}

extern "C" void kernel_launch(void* const* d_in, const int* in_sizes, int n_in,
                              void* d_out, int out_size, void* d_ws, size_t ws_size,
                              hipStream_t stream)
{
    const float* cls_  = (const float*)d_in[0];
    const float* reg_  = (const float*)d_in[1];
    const float* anch_ = (const float*)d_in[2];
    const float* ann_  = (const float*)d_in[3];
    float* ws  = (float*)d_ws;
    float* out = (float*)d_out;

    focal_prep<<<NB, 64, 0, stream>>>(ann_, ws);
    dim3 grid(NBLK_X, NB);
    focal_main<<<grid, dim3(TPB), 0, stream>>>(cls_, reg_, anch_, ws, ws);
    focal_finalize<<<1, 64, 0, stream>>>(ws, out);
}

// Round 11
// 41.102 us; speedup vs baseline: 1.5447x; 1.1558x over previous
//
#include <hip/hip_runtime.h>

#define NB 16
#define NA 76725
#define NC 8
#define NM 32
#define FEPS 1e-4f
#define TPB 256
#define SEQ 4                         // anchors per thread, sequential + prefetch
#define ANCH_PER_BLK (TPB * SEQ)      // 1024
#define NBLK_X ((NA + ANCH_PER_BLK - 1) / ANCH_PER_BLK)   // 75

// ws layout (floats):
//  [WS_ACC .. +NB*16)   per-image acc: {cls_sum, reg_sum, npos(uint), pad..} 64B stride
//  [WS_NVP .. +16)      padded valid count per image
//  [WS_CNT .. +16)      num_valid per image
//  [WS_REC .. +NB*NM*8) per (b,m) record {x1,y1,x2+1,y2+1,area2,lab,pad,pad} (32B)
//  [WS_EPI .. +NB*NM*4) per (b,m) float4 {gcx,gcy,log(gw),log(gh)}
#define WS_ACC 0
#define WS_NVP (NB * 16)
#define WS_CNT (WS_NVP + 16)
#define WS_REC (WS_CNT + 16)
#define WS_EPI (WS_REC + NB * NM * 8)

__global__ __launch_bounds__(64) void focal_prep(
    const float* __restrict__ ann_, float* __restrict__ ws)
{
    const int b = blockIdx.x;
    const int m = threadIdx.x;
    if (m < 16) ws[WS_ACC + b * 16 + m] = 0.f;
    bool valid = false;
    float x1 = 0.f, y1 = 0.f, x2 = 0.f, y2 = 0.f, lab = -1.f;
    if (m < NM) {
        const float* r = ann_ + ((size_t)b * NM + m) * 5;
        x1 = r[0]; y1 = r[1]; x2 = r[2]; y2 = r[3]; lab = r[4];
        valid = lab > -0.5f;
        float* rec = ws + WS_REC + ((size_t)b * NM + m) * 8;
        rec[0] = 3e18f; rec[1] = 3e18f; rec[2] = -3e18f; rec[3] = -3e18f;
        rec[4] = 1.0f;  rec[5] = -1.f;  rec[6] = 0.f;    rec[7] = 0.f;
        reinterpret_cast<float4*>(ws + WS_EPI)[b * NM + m] = make_float4(0.f, 0.f, 0.f, 0.f);
    }
    const unsigned long long mask = __ballot(valid);
    const int cnt = __popcll(mask);
    __syncthreads();
    if (valid) {
        const int idx = __popcll(mask & ((1ull << m) - 1ull));  // stable compaction
        float* rec = ws + WS_REC + ((size_t)b * NM + idx) * 8;
        rec[0] = x1; rec[1] = y1; rec[2] = x2 + 1.f; rec[3] = y2 + 1.f;
        rec[4] = (x2 - x1 + 1.f) * (y2 - y1 + 1.f);
        rec[5] = lab;
        const float w0 = x2 - x1, h0 = y2 - y1;
        reinterpret_cast<float4*>(ws + WS_EPI)[b * NM + idx] =
            make_float4(x1 + 0.5f * w0, y1 + 0.5f * h0,
                        __logf(fmaxf(w0, 1.f)), __logf(fmaxf(h0, 1.f)));
    }
    if (m == 0) {
        ws[WS_CNT + b] = (float)cnt;
        ws[WS_NVP + b] = (float)((cnt + 7) & ~7);
    }
}

// Sequential SEQ=4 anchors/thread with double-buffered prefetch: loads for
// anchor s+1 are in flight while anchor s computes -> memory stays busy for
// the whole wave lifetime (fixes the ~0.9 TB/s duty-cycle limit of R7-R10).
__global__ __launch_bounds__(TPB, 4) void focal_main(
    const float* __restrict__ cls_,
    const float* __restrict__ reg_,
    const float* __restrict__ anch_,
    const float* __restrict__ tab,
    float* __restrict__ acc)
{
    const int b   = blockIdx.y;
    const int tid = threadIdx.x;

    const float4* __restrict__ anch4 = reinterpret_cast<const float4*>(anch_);
    const float4* __restrict__ reg4  = reinterpret_cast<const float4*>(reg_);
    const float4* __restrict__ cls4  = reinterpret_cast<const float4*>(cls_);

    const int ab = blockIdx.x * ANCH_PER_BLK + tid;
    bool mk0, mk1, mk2, mk3;
    auto addr = [&](int s, bool& msk) -> size_t {
        const int a = ab + s * TPB;
        msk = (a < NA);
        return (size_t)b * NA + (msk ? a : (NA - 1));
    };

    // ---- step-0 loads first: their latency overlaps table staging + barrier
    const size_t b0 = addr(0, mk0);
    float4 anA = anch4[b0], rgA = reg4[b0], cv0A = cls4[b0 * 2], cv1A = cls4[b0 * 2 + 1];

    __shared__ float  s_x1[NM], s_y1[NM], s_x21[NM], s_y21[NM], s_a2[NM], s_lab[NM];
    __shared__ float4 s_epi[NM];
    if (tid < NM) {
        const float4 r0 = reinterpret_cast<const float4*>(tab + WS_REC)[(b * NM + tid) * 2];
        const float4 r1 = reinterpret_cast<const float4*>(tab + WS_REC)[(b * NM + tid) * 2 + 1];
        s_x1[tid] = r0.x; s_y1[tid] = r0.y; s_x21[tid] = r0.z; s_y21[tid] = r0.w;
        s_a2[tid] = r1.x; s_lab[tid] = r1.y;
        s_epi[tid] = reinterpret_cast<const float4*>(tab + WS_EPI)[b * NM + tid];
    }
    int nvp = (int)tab[WS_NVP + b];
    nvp = __builtin_amdgcn_readfirstlane(nvp);   // wave-uniform scalar loop bound
    __syncthreads();                             // drains step-0 loads + staging

    float cls_c = 0.f, reg_c = 0.f;
    unsigned pos_c = 0;

    // compute one anchor from registers (R7's exact math, APT=1 body)
    auto compute = [&](const float4& an, const float4& rg,
                       const float4& cv0, const float4& cv1, bool msk) {
        const float ax = an.x, ay = an.y;
        const float az1 = an.z + 1.f, aw1 = an.w + 1.f;
        const float area1 = (an.z - ax + 1.f) * (an.w - ay + 1.f);

        float ib = 0.f, ub = 1.f;
        int arg = 0;
        #pragma unroll 4
        for (int m = 0; m < nvp; ++m) {
            const float x1 = s_x1[m], y1 = s_y1[m];      // LDS broadcast reads
            const float x21 = s_x21[m], y21 = s_y21[m];
            const float a2 = s_a2[m];
            const float w = fminf(az1, x21) - fmaxf(ax, x1);
            const float h = fminf(aw1, y21) - fmaxf(ay, y1);
            const float inter = fmaxf(w, 0.f) * fmaxf(h, 0.f);
            const float u = area1 + a2 - inter;
            const bool better = inter * ub > ib * u;     // strict >: first-occurrence
            ib  = better ? inter : ib;
            ub  = better ? u : ub;
            arg = better ? m : arg;
        }
        const bool pos = ib >= 0.4f * ub;
        const bool neg = ib <  0.3f * ub;
        const bool act = (pos || neg) && msk;

        {
            const float pv[8] = {cv0.x, cv0.y, cv0.z, cv0.w, cv1.x, cv1.y, cv1.z, cv1.w};
            float pcl[8];
            float bsum = 0.f;
            #pragma unroll
            for (int c = 0; c < NC; ++c) {
                const float p = fminf(fmaxf(pv[c], FEPS), 1.f - FEPS);
                pcl[c] = p;
                bsum += 0.75f * p * p * (-__logf(1.f - p));
            }
            float contrib = bsum;
            if (pos) {
                const int labi = (int)s_lab[arg];
                const float t0 = (labi & 1) ? pcl[1] : pcl[0];
                const float t1 = (labi & 1) ? pcl[3] : pcl[2];
                const float t2 = (labi & 1) ? pcl[5] : pcl[4];
                const float t3 = (labi & 1) ? pcl[7] : pcl[6];
                const float u0 = (labi & 2) ? t1 : t0;
                const float u1 = (labi & 2) ? t3 : t2;
                const float pt = (labi & 4) ? u1 : u0;
                const float om = 1.f - pt;
                contrib += 0.25f * om * om * (-__logf(pt))
                         - 0.75f * pt * pt * (-__logf(om));
            }
            cls_c += act ? contrib : 0.f;
        }
        if (pos && msk) {
            pos_c += 1;
            const float4 ep = s_epi[arg];
            const float awd = az1 - 1.f - ax;
            const float ahd = aw1 - 1.f - ay;
            const float acx = ax + 0.5f * awd;
            const float acy = ay + 0.5f * ahd;
            const float t0 = __fdividef(ep.x - acx, awd) * 10.f;
            const float t1 = __fdividef(ep.y - acy, ahd) * 10.f;
            const float t2 = (ep.z - __logf(awd)) * 5.f;
            const float t3 = (ep.w - __logf(ahd)) * 5.f;
            const float d0 = fabsf(t0 - rg.x);
            const float d1 = fabsf(t1 - rg.y);
            const float d2 = fabsf(t2 - rg.z);
            const float d3 = fabsf(t3 - rg.w);
            auto sl1 = [](float d) {
                return d <= (1.f / 9.f) ? 4.5f * d * d : d - (0.5f / 9.f);
            };
            reg_c += sl1(d0) + sl1(d1) + sl1(d2) + sl1(d3);
        }
    };

    // ---- software pipeline: prefetch s+1 into the other buffer, compute s
    const size_t b1 = addr(1, mk1);
    float4 anB = anch4[b1], rgB = reg4[b1], cv0B = cls4[b1 * 2], cv1B = cls4[b1 * 2 + 1];
    __builtin_amdgcn_sched_barrier(0);     // pin: prefetch stays above compute
    compute(anA, rgA, cv0A, cv1A, mk0);

    const size_t b2 = addr(2, mk2);
    anA = anch4[b2]; rgA = reg4[b2]; cv0A = cls4[b2 * 2]; cv1A = cls4[b2 * 2 + 1];
    __builtin_amdgcn_sched_barrier(0);
    compute(anB, rgB, cv0B, cv1B, mk1);

    const size_t b3 = addr(3, mk3);
    anB = anch4[b3]; rgB = reg4[b3]; cv0B = cls4[b3 * 2]; cv1B = cls4[b3 * 2 + 1];
    __builtin_amdgcn_sched_barrier(0);
    compute(anA, rgA, cv0A, cv1A, mk2);

    compute(anB, rgB, cv0B, cv1B, mk3);

    // wave-64 shuffle reduction, cross-wave via LDS, 3 atomics per block
    #pragma unroll
    for (int off = 32; off > 0; off >>= 1) {
        cls_c += __shfl_down(cls_c, off);
        reg_c += __shfl_down(reg_c, off);
        pos_c += __shfl_down(pos_c, off);
    }
    __shared__ float    sc[4], sr[4];
    __shared__ unsigned sp[4];
    const int wave = tid >> 6, lane = tid & 63;
    if (lane == 0) { sc[wave] = cls_c; sr[wave] = reg_c; sp[wave] = pos_c; }
    __syncthreads();
    if (tid == 0) {
        const float    c = sc[0] + sc[1] + sc[2] + sc[3];
        const float    r = sr[0] + sr[1] + sr[2] + sr[3];
        const unsigned p = sp[0] + sp[1] + sp[2] + sp[3];
        atomicAdd(&acc[WS_ACC + b * 16 + 0], c);
        atomicAdd(&acc[WS_ACC + b * 16 + 1], r);
        atomicAdd(reinterpret_cast<unsigned*>(acc) + WS_ACC + b * 16 + 2, p);
    }
}

__global__ __launch_bounds__(64) void focal_finalize(
    const float* __restrict__ ws, float* __restrict__ out)
{
    __shared__ float s_cls[NB], s_reg[NB];
    const int b = threadIdx.x;
    if (b < NB) {
        const float    nv      = ws[WS_CNT + b];
        const float    cls_sum = ws[WS_ACC + b * 16 + 0];
        const float    reg_sum = ws[WS_ACC + b * 16 + 1];
        const unsigned npos    = reinterpret_cast<const unsigned*>(ws)[WS_ACC + b * 16 + 2];
        float cl = cls_sum / fmaxf((float)npos, 1.f);
        float rl = (npos > 0u) ? reg_sum / (float)(npos * 4u) : 0.f;
        if (nv < 0.5f) { cl = 0.f; rl = 0.f; }
        s_cls[b] = cl;
        s_reg[b] = rl;
    }
    __syncthreads();
    if (threadIdx.x == 0) {
        float c = 0.f, r = 0.f;
        for (int i = 0; i < NB; ++i) { c += s_cls[i]; r += s_reg[i]; }
        out[0] = c * (1.f / NB);
        out[1] = r * (1.f / NB);
    }
}

extern "C" void kernel_launch(void* const* d_in, const int* in_sizes, int n_in,
                              void* d_out, int out_size, void* d_ws, size_t ws_size,
                              hipStream_t stream)
{
    const float* cls_  = (const float*)d_in[0];
    const float* reg_  = (const float*)d_in[1];
    const float* anch_ = (const float*)d_in[2];
    const float* ann_  = (const float*)d_in[3];
    float* ws  = (float*)d_ws;
    float* out = (float*)d_out;

    focal_prep<<<NB, 64, 0, stream>>>(ann_, ws);
    dim3 grid(NBLK_X, NB);
    focal_main<<<grid, dim3(TPB), 0, stream>>>(cls_, reg_, anch_, ws, ws);
    focal_finalize<<<1, 64, 0, stream>>>(ws, out);
}

// Round 12
// 40.597 us; speedup vs baseline: 1.5639x; 1.0124x over previous
//
#include <hip/hip_runtime.h>

#define NB 16
#define NA 76725
#define NC 8
#define NM 32
#define FEPS 1e-4f
#define TPB 256
#define NBX 96                       // blocks per image; 96*16 = 1536 = 6 * 256 CUs
#define APB 800                      // anchors per block = 3*TPB + 32 tail

// d_ws: float4 partial[NB*NBX]  {cls_sum, reg_sum, npos, cnt} — written every call

// Fused kernel: wave 0 rebuilds the annotation table (sentinel-padded, compacted)
// while other waves' step-0 loads are in flight. Then R11's proven sequential
// prefetch pipeline: load s+1 || compute s. Tail (32 anchors) on wave 0 only.
__global__ __launch_bounds__(TPB, 4) void focal_main(
    const float* __restrict__ cls_,
    const float* __restrict__ reg_,
    const float* __restrict__ anch_,
    const float* __restrict__ ann_,
    float4* __restrict__ partial)
{
    const int b   = blockIdx.y;
    const int xb  = blockIdx.x;
    const int tid = threadIdx.x;

    const float4* __restrict__ anch4 = reinterpret_cast<const float4*>(anch_);
    const float4* __restrict__ reg4  = reinterpret_cast<const float4*>(reg_);
    const float4* __restrict__ cls4  = reinterpret_cast<const float4*>(cls_);

    const int ab = xb * APB;

    // ---- step-0 loads first: latency overlaps table staging + barrier
    const int a0 = ab + tid;
    const bool mk0 = (a0 < NA);
    const size_t b0 = (size_t)b * NA + (mk0 ? a0 : (NA - 1));
    float4 anA = anch4[b0], rgA = reg4[b0], c0A = cls4[b0 * 2], c1A = cls4[b0 * 2 + 1];

    // ---- fused table staging (wave 0 only; 640B of ann_, L2-hot)
    __shared__ float  s_x1[NM], s_y1[NM], s_x21[NM], s_y21[NM], s_a2[NM], s_lab[NM];
    __shared__ float4 s_epi[NM];
    __shared__ int    s_nvp, s_cnt;
    if (tid < 64) {
        bool valid = false;
        float x1 = 0.f, y1 = 0.f, x2 = 0.f, y2 = 0.f, lab = -1.f;
        if (tid < NM) {
            const float* r = ann_ + ((size_t)b * NM + tid) * 5;
            x1 = r[0]; y1 = r[1]; x2 = r[2]; y2 = r[3]; lab = r[4];
            valid = lab > -0.5f;
        }
        const unsigned long long mask = __ballot(valid);
        const int cnt = __popcll(mask);
        if (tid < NM) {        // sentinel fill first (program order within wave)
            s_x1[tid] = 3e18f; s_y1[tid] = 3e18f; s_x21[tid] = -3e18f; s_y21[tid] = -3e18f;
            s_a2[tid] = 1.f;   s_lab[tid] = -1.f;
            s_epi[tid] = make_float4(0.f, 0.f, 0.f, 0.f);
        }
        if (valid) {           // stable compaction overwrite (later instruction wins)
            const int idx = __popcll(mask & ((1ull << tid) - 1ull));
            s_x1[idx] = x1; s_y1[idx] = y1; s_x21[idx] = x2 + 1.f; s_y21[idx] = y2 + 1.f;
            s_a2[idx] = (x2 - x1 + 1.f) * (y2 - y1 + 1.f);
            s_lab[idx] = lab;
            const float w0 = x2 - x1, h0 = y2 - y1;
            s_epi[idx] = make_float4(x1 + 0.5f * w0, y1 + 0.5f * h0,
                                     __logf(fmaxf(w0, 1.f)), __logf(fmaxf(h0, 1.f)));
        }
        if (tid == 0) { s_nvp = (cnt + 7) & ~7; s_cnt = cnt; }
    }
    __syncthreads();                             // table ready; step-0 loads drained
    int nvp = __builtin_amdgcn_readfirstlane(s_nvp);

    float cls_c = 0.f, reg_c = 0.f;
    unsigned pos_c = 0;

    // compute one anchor from registers (R7/R11's exact math)
    auto compute = [&](const float4& an, const float4& rg,
                       const float4& cv0, const float4& cv1, bool msk) {
        const float ax = an.x, ay = an.y;
        const float az1 = an.z + 1.f, aw1 = an.w + 1.f;
        const float area1 = (an.z - ax + 1.f) * (an.w - ay + 1.f);

        float ib = 0.f, ub = 1.f;
        int arg = 0;
        #pragma unroll 4
        for (int m = 0; m < nvp; ++m) {
            const float x1 = s_x1[m], y1 = s_y1[m];      // LDS broadcast reads
            const float x21 = s_x21[m], y21 = s_y21[m];
            const float a2 = s_a2[m];
            const float w = fminf(az1, x21) - fmaxf(ax, x1);
            const float h = fminf(aw1, y21) - fmaxf(ay, y1);
            const float inter = fmaxf(w, 0.f) * fmaxf(h, 0.f);
            const float u = area1 + a2 - inter;
            const bool better = inter * ub > ib * u;     // strict >: first-occurrence
            ib  = better ? inter : ib;
            ub  = better ? u : ub;
            arg = better ? m : arg;
        }
        const bool pos = ib >= 0.4f * ub;
        const bool neg = ib <  0.3f * ub;
        const bool act = (pos || neg) && msk;

        {
            const float pv[8] = {cv0.x, cv0.y, cv0.z, cv0.w, cv1.x, cv1.y, cv1.z, cv1.w};
            float pcl[8];
            float bsum = 0.f;
            #pragma unroll
            for (int c = 0; c < NC; ++c) {
                const float p = fminf(fmaxf(pv[c], FEPS), 1.f - FEPS);
                pcl[c] = p;
                bsum += 0.75f * p * p * (-__logf(1.f - p));
            }
            float contrib = bsum;
            if (pos) {
                const int labi = (int)s_lab[arg];
                const float t0 = (labi & 1) ? pcl[1] : pcl[0];
                const float t1 = (labi & 1) ? pcl[3] : pcl[2];
                const float t2 = (labi & 1) ? pcl[5] : pcl[4];
                const float t3 = (labi & 1) ? pcl[7] : pcl[6];
                const float u0 = (labi & 2) ? t1 : t0;
                const float u1 = (labi & 2) ? t3 : t2;
                const float pt = (labi & 4) ? u1 : u0;
                const float om = 1.f - pt;
                contrib += 0.25f * om * om * (-__logf(pt))
                         - 0.75f * pt * pt * (-__logf(om));
            }
            cls_c += act ? contrib : 0.f;
        }
        if (pos && msk) {
            pos_c += 1;
            const float4 ep = s_epi[arg];
            const float awd = az1 - 1.f - ax;
            const float ahd = aw1 - 1.f - ay;
            const float acx = ax + 0.5f * awd;
            const float acy = ay + 0.5f * ahd;
            const float t0 = __fdividef(ep.x - acx, awd) * 10.f;
            const float t1 = __fdividef(ep.y - acy, ahd) * 10.f;
            const float t2 = (ep.z - __logf(awd)) * 5.f;
            const float t3 = (ep.w - __logf(ahd)) * 5.f;
            const float d0 = fabsf(t0 - rg.x);
            const float d1 = fabsf(t1 - rg.y);
            const float d2 = fabsf(t2 - rg.z);
            const float d3 = fabsf(t3 - rg.w);
            auto sl1 = [](float d) {
                return d <= (1.f / 9.f) ? 4.5f * d * d : d - (0.5f / 9.f);
            };
            reg_c += sl1(d0) + sl1(d1) + sl1(d2) + sl1(d3);
        }
    };

    // ---- software pipeline: load s+1 || compute s (R11 proven)
    const int a1 = ab + TPB + tid;
    const bool mk1 = (a1 < NA);
    const size_t b1 = (size_t)b * NA + (mk1 ? a1 : (NA - 1));
    float4 anB = anch4[b1], rgB = reg4[b1], c0B = cls4[b1 * 2], c1B = cls4[b1 * 2 + 1];
    __builtin_amdgcn_sched_barrier(0);     // pin prefetch above compute
    compute(anA, rgA, c0A, c1A, mk0);

    const int a2i = ab + 2 * TPB + tid;
    const bool mk2 = (a2i < NA);
    const size_t b2 = (size_t)b * NA + (mk2 ? a2i : (NA - 1));
    anA = anch4[b2]; rgA = reg4[b2]; c0A = cls4[b2 * 2]; c1A = cls4[b2 * 2 + 1];
    __builtin_amdgcn_sched_barrier(0);
    compute(anB, rgB, c0B, c1B, mk1);

    // tail: 32 anchors, wave 0 lanes 0-31 only
    bool mk3 = false;
    if (tid < 32) {
        const int a3 = ab + 3 * TPB + tid;
        mk3 = (a3 < NA);
        const size_t b3 = (size_t)b * NA + (mk3 ? a3 : (NA - 1));
        anB = anch4[b3]; rgB = reg4[b3]; c0B = cls4[b3 * 2]; c1B = cls4[b3 * 2 + 1];
    }
    __builtin_amdgcn_sched_barrier(0);
    compute(anA, rgA, c0A, c1A, mk2);
    if (tid < 32) compute(anB, rgB, c0B, c1B, mk3);

    // wave-64 shuffle reduction, cross-wave via LDS, one float4 store per block
    #pragma unroll
    for (int off = 32; off > 0; off >>= 1) {
        cls_c += __shfl_down(cls_c, off);
        reg_c += __shfl_down(reg_c, off);
        pos_c += __shfl_down(pos_c, off);
    }
    __shared__ float    sc[4], sr[4];
    __shared__ unsigned sp[4];
    const int wave = tid >> 6, lane = tid & 63;
    if (lane == 0) { sc[wave] = cls_c; sr[wave] = reg_c; sp[wave] = pos_c; }
    __syncthreads();
    if (tid == 0) {
        const float    c = sc[0] + sc[1] + sc[2] + sc[3];
        const float    r = sr[0] + sr[1] + sr[2] + sr[3];
        const unsigned p = sp[0] + sp[1] + sp[2] + sp[3];
        partial[b * NBX + xb] = make_float4(c, r, (float)p, (float)s_cnt);
    }
}

__global__ __launch_bounds__(64) void focal_finalize(
    const float4* __restrict__ partial, float* __restrict__ out)
{
    const int t = threadIdx.x;          // 64 threads
    const int b = t & 15, q = t >> 4;   // 4 strided groups per image
    float cs = 0.f, rs = 0.f, np = 0.f;
    for (int x = q; x < NBX; x += 4) {
        const float4 v = partial[b * NBX + x];
        cs += v.x; rs += v.y; np += v.z;
    }
    cs += __shfl_down(cs, 32); rs += __shfl_down(rs, 32); np += __shfl_down(np, 32);
    cs += __shfl_down(cs, 16); rs += __shfl_down(rs, 16); np += __shfl_down(np, 16);
    float cl = 0.f, rl = 0.f;
    if (t < 16) {
        const float cnt = partial[b * NBX].w;   // num_valid (same in every slot of b)
        cl = cs / fmaxf(np, 1.f);
        rl = (np > 0.5f) ? rs / (np * 4.f) : 0.f;
        if (cnt < 0.5f) { cl = 0.f; rl = 0.f; }
    }
    #pragma unroll
    for (int off = 8; off > 0; off >>= 1) {
        cl += __shfl_down(cl, off);
        rl += __shfl_down(rl, off);
    }
    if (t == 0) {
        out[0] = cl * (1.f / NB);
        out[1] = rl * (1.f / NB);
    }
}

extern "C" void kernel_launch(void* const* d_in, const int* in_sizes, int n_in,
                              void* d_out, int out_size, void* d_ws, size_t ws_size,
                              hipStream_t stream)
{
    const float* cls_  = (const float*)d_in[0];
    const float* reg_  = (const float*)d_in[1];
    const float* anch_ = (const float*)d_in[2];
    const float* ann_  = (const float*)d_in[3];
    float4* partial = (float4*)d_ws;
    float*  out     = (float*)d_out;

    dim3 grid(NBX, NB);
    focal_main<<<grid, dim3(TPB), 0, stream>>>(cls_, reg_, anch_, ann_, partial);
    focal_finalize<<<1, 64, 0, stream>>>(partial, out);
}